// Round 1
// baseline (2706.959 us; speedup 1.0000x reference)
//
#include <hip/hip_runtime.h>
#include <cstdint>

#define BM 128
#define BN 128
#define BK 8
#define TM 8
#define TN 8

enum { EP_PLAIN = 0, EP_SPLIT_SILU = 1, EP_SOFTPLUS = 2, EP_BIAS = 3 };

__device__ __forceinline__ float silu_f(float x) { return x / (1.f + __expf(-x)); }
__device__ __forceinline__ float softplus_f(float x) {
    return (x > 20.f) ? x : log1pf(__expf(x));
}

// C = A(MxK, lda) * B(KxN, ldb), fused epilogue.
// Requires M % BM == 0, K % BK == 0, N % 4 == 0. N may be < gridDim.x*BN (masked).
template <int MODE>
__global__ __launch_bounds__(256) void sgemm_ep(
    const float* __restrict__ A, int lda,
    const float* __restrict__ B, int ldb,
    float* __restrict__ C, int ldc,
    const float* __restrict__ bias,
    float* __restrict__ out2,  // second output for split mode
    int M, int N, int K, int Esplit)
{
    __shared__ float As[BK][BM];
    __shared__ float Bs[BK][BN];
    const int tid = threadIdx.x;
    const int m0 = blockIdx.y * BM;
    const int n0 = blockIdx.x * BN;
    const int ar = tid >> 1, ac = (tid & 1) * 4;
    const int br = tid >> 5, bc = (tid & 31) * 4;
    const int tm = (tid >> 4) * TM;
    const int tn = (tid & 15) * TN;

    float acc[TM][TN];
#pragma unroll
    for (int i = 0; i < TM; i++)
#pragma unroll
        for (int j = 0; j < TN; j++) acc[i][j] = 0.f;

    for (int k0 = 0; k0 < K; k0 += BK) {
        // A tile: 128 rows x 8 cols, stored transposed
        const float* Ap = A + (size_t)(m0 + ar) * lda + (k0 + ac);
        float4 av = *(const float4*)Ap;
        As[ac + 0][ar] = av.x;
        As[ac + 1][ar] = av.y;
        As[ac + 2][ar] = av.z;
        As[ac + 3][ar] = av.w;
        // B tile: 8 rows x 128 cols
        float4 bv = make_float4(0.f, 0.f, 0.f, 0.f);
        const int gc = n0 + bc;
        if (gc < N) bv = *(const float4*)(B + (size_t)(k0 + br) * ldb + gc);
        *(float4*)&Bs[br][bc] = bv;
        __syncthreads();
#pragma unroll
        for (int kk = 0; kk < BK; kk++) {
            float4 a0 = *(const float4*)&As[kk][tm];
            float4 a1 = *(const float4*)&As[kk][tm + 4];
            float4 b0 = *(const float4*)&Bs[kk][tn];
            float4 b1 = *(const float4*)&Bs[kk][tn + 4];
            float a[TM] = {a0.x, a0.y, a0.z, a0.w, a1.x, a1.y, a1.z, a1.w};
            float b[TN] = {b0.x, b0.y, b0.z, b0.w, b1.x, b1.y, b1.z, b1.w};
#pragma unroll
            for (int i = 0; i < TM; i++)
#pragma unroll
                for (int j = 0; j < TN; j++) acc[i][j] = fmaf(a[i], b[j], acc[i][j]);
        }
        __syncthreads();
    }

#pragma unroll
    for (int i = 0; i < TM; i++) {
        const int row = m0 + tm + i;
#pragma unroll
        for (int j = 0; j < TN; j++) {
            const int col = n0 + tn + j;
            if (col >= N) continue;
            float v = acc[i][j];
            if (MODE == EP_SPLIT_SILU) {
                v += bias[col];
                if (col < Esplit)
                    C[(size_t)row * Esplit + col] = v;
                else
                    out2[(size_t)row * Esplit + (col - Esplit)] = silu_f(v);
            } else if (MODE == EP_SOFTPLUS) {
                C[(size_t)row * ldc + col] = softplus_f(v + bias[col]);
            } else if (MODE == EP_BIAS) {
                C[(size_t)row * ldc + col] = v + bias[col];
            } else {
                C[(size_t)row * ldc + col] = v;
            }
        }
    }
}

// Depthwise causal conv (K=4) along L + bias + SiLU.
// xin, xo: (B*L, E) row-major. w: (E, 4). cb: (E).
__global__ __launch_bounds__(256) void conv_silu(
    const float* __restrict__ xin, const float* __restrict__ w,
    const float* __restrict__ cb, float* __restrict__ xo,
    int Ln, int En, size_t total)
{
    for (size_t idx = (size_t)blockIdx.x * 256 + threadIdx.x; idx < total;
         idx += (size_t)gridDim.x * 256) {
        const int e = (int)(idx % En);
        const size_t row = idx / En;
        const int l = (int)(row % Ln);
        float acc = cb[e];
        const float* wp = w + (size_t)e * 4;
#pragma unroll
        for (int k = 0; k < 4; k++) {
            const int li = l - 3 + k;
            if (li >= 0) acc = fmaf(wp[k], xin[(row - 3 + k) * (size_t)En + e], acc);
        }
        xo[idx] = silu_f(acc);
    }
}

// Selective scan. 16 lanes per channel (lane = state n). Block = 256 thr = 16 channels.
// u, delta, xr, yg: (B*L, E). proj: (B*L, 160) with dt[0:128], Bm[128:144], Cm[144:160].
__global__ __launch_bounds__(256) void scan_kernel(
    const float* __restrict__ u, const float* __restrict__ delta,
    const float* __restrict__ proj, const float* __restrict__ A_log,
    const float* __restrict__ Dp, const float* __restrict__ xr,
    float* __restrict__ yg, int Lb, int Eb)
{
    const int lane = threadIdx.x & 15;
    const int grp = threadIdx.x >> 4;  // 0..15
    const int blocks_per_b = Eb / 16;
    const int b = blockIdx.x / blocks_per_b;
    const int e = (blockIdx.x % blocks_per_b) * 16 + grp;

    const float An = -expf(A_log[(size_t)e * 16 + lane]);
    const float De = Dp[e];
    float h = 0.f;

    const size_t base = ((size_t)b * Lb) * Eb + e;
    const size_t pbase = ((size_t)b * Lb) * 160;

    float d = delta[base];
    float uu = u[base];
    float Bn = proj[pbase + 128 + lane];
    float Cn = proj[pbase + 144 + lane];

    for (int t = 0; t < Lb; t++) {
        float dn = 0.f, un = 0.f, Bnn = 0.f, Cnn = 0.f;
        if (t + 1 < Lb) {
            const size_t b2 = base + (size_t)(t + 1) * Eb;
            dn = delta[b2];
            un = u[b2];
            const size_t p2 = pbase + (size_t)(t + 1) * 160;
            Bnn = proj[p2 + 128 + lane];
            Cnn = proj[p2 + 144 + lane];
        }
        const float dA = __expf(d * An);
        h = fmaf(dA, h, d * uu * Bn);
        float yp = h * Cn;
#pragma unroll
        for (int off = 8; off >= 1; off >>= 1) yp += __shfl_xor(yp, off, 16);
        if (lane == 0) {
            const size_t o = base + (size_t)t * Eb;
            yg[o] = (yp + uu * De) * xr[o];
        }
        d = dn; uu = un; Bn = Bnn; Cn = Cnn;
    }
}

extern "C" void kernel_launch(void* const* d_in, const int* in_sizes, int n_in,
                              void* d_out, int out_size, void* d_ws, size_t ws_size,
                              hipStream_t stream)
{
    const int Bc = 2, Lc = 2048, Hc = 1024, Ec = 2048;
    const int M = Bc * Lc;      // 4096
    const int PN = 160;         // DT_RANK + 2N
    const int DTR = 128;

    const float* x        = (const float*)d_in[0];
    const float* W_in     = (const float*)d_in[1];
    const float* b_in     = (const float*)d_in[2];
    const float* conv_w   = (const float*)d_in[3];
    const float* conv_b   = (const float*)d_in[4];
    const float* x_proj_w = (const float*)d_in[5];
    const float* dt_proj_w= (const float*)d_in[6];
    const float* dt_bias  = (const float*)d_in[7];
    const float* A_log    = (const float*)d_in[8];
    const float* D_param  = (const float*)d_in[9];
    const float* W_out    = (const float*)d_in[10];
    const float* b_out    = (const float*)d_in[11];
    float* out = (float*)d_out;

    float* ws = (float*)d_ws;
    const size_t ME = (size_t)M * Ec;
    float* xc_raw = ws;                 // M*E  (reused later as yg)
    float* xr     = xc_raw + ME;        // M*E
    float* xc     = xr + ME;            // M*E
    float* delta  = xc + ME;            // M*E
    float* proj   = delta + ME;         // M*160
    float* yg     = xc_raw;             // reuse

    // 1) z = x @ W_in + b_in ; split -> xc_raw, silu -> xr
    sgemm_ep<EP_SPLIT_SILU><<<dim3(2 * Ec / BN, M / BM), 256, 0, stream>>>(
        x, Hc, W_in, 2 * Ec, xc_raw, Ec, b_in, xr, M, 2 * Ec, Hc, Ec);

    // 2) depthwise causal conv + bias + silu -> xc
    conv_silu<<<2048, 256, 0, stream>>>(xc_raw, conv_w, conv_b, xc, Lc, Ec, ME);

    // 3) proj = xc @ x_proj_w  (N=160, masked)
    sgemm_ep<EP_PLAIN><<<dim3((PN + BN - 1) / BN, M / BM), 256, 0, stream>>>(
        xc, Ec, x_proj_w, PN, proj, PN, nullptr, nullptr, M, PN, Ec, 0);

    // 4) delta = softplus(dt @ dt_proj_w + dt_bias)
    sgemm_ep<EP_SOFTPLUS><<<dim3(Ec / BN, M / BM), 256, 0, stream>>>(
        proj, PN, dt_proj_w, Ec, delta, Ec, dt_bias, nullptr, M, Ec, DTR, 0);

    // 5) selective scan + *xr -> yg
    scan_kernel<<<Bc * (Ec / 16), 256, 0, stream>>>(
        xc, delta, proj, A_log, D_param, xr, yg, Lc, Ec);

    // 6) out = yg @ W_out + b_out
    sgemm_ep<EP_BIAS><<<dim3(Hc / BN, M / BM), 256, 0, stream>>>(
        yg, Ec, W_out, Hc, out, Hc, b_out, nullptr, M, Hc, Ec, 0);
}

// Round 2
// 1354.764 us; speedup vs baseline: 1.9981x; 1.9981x over previous
//
#include <hip/hip_runtime.h>
#include <cstdint>

#define BM 128
#define BN 128
#define BK 8
#define TM 8
#define TN 8

// scan geometry
#define SL 2048   // sequence length
#define SE 2048   // channels E
#define SB 2      // batch
#define SN 16     // states
#define SC 64     // chunks
#define ST 32     // steps per chunk (SC*ST == SL)

enum { EP_PLAIN = 0, EP_SPLIT_SILU = 1, EP_SOFTPLUS = 2, EP_BIAS = 3 };

__device__ __forceinline__ float silu_f(float x) { return x / (1.f + __expf(-x)); }
__device__ __forceinline__ float softplus_f(float x) {
    return (x > 20.f) ? x : log1pf(__expf(x));
}

// C = A(MxK, lda) * B(KxN, ldb), fused epilogue.
template <int MODE>
__global__ __launch_bounds__(256) void sgemm_ep(
    const float* __restrict__ A, int lda,
    const float* __restrict__ B, int ldb,
    float* __restrict__ C, int ldc,
    const float* __restrict__ bias,
    float* __restrict__ out2,
    int M, int N, int K, int Esplit)
{
    __shared__ float As[BK][BM];
    __shared__ float Bs[BK][BN];
    const int tid = threadIdx.x;
    const int m0 = blockIdx.y * BM;
    const int n0 = blockIdx.x * BN;
    const int ar = tid >> 1, ac = (tid & 1) * 4;
    const int br = tid >> 5, bc = (tid & 31) * 4;
    const int tm = (tid >> 4) * TM;
    const int tn = (tid & 15) * TN;

    float acc[TM][TN];
#pragma unroll
    for (int i = 0; i < TM; i++)
#pragma unroll
        for (int j = 0; j < TN; j++) acc[i][j] = 0.f;

    for (int k0 = 0; k0 < K; k0 += BK) {
        const float* Ap = A + (size_t)(m0 + ar) * lda + (k0 + ac);
        float4 av = *(const float4*)Ap;
        As[ac + 0][ar] = av.x;
        As[ac + 1][ar] = av.y;
        As[ac + 2][ar] = av.z;
        As[ac + 3][ar] = av.w;
        float4 bv = make_float4(0.f, 0.f, 0.f, 0.f);
        const int gc = n0 + bc;
        if (gc < N) bv = *(const float4*)(B + (size_t)(k0 + br) * ldb + gc);
        *(float4*)&Bs[br][bc] = bv;
        __syncthreads();
#pragma unroll
        for (int kk = 0; kk < BK; kk++) {
            float4 a0 = *(const float4*)&As[kk][tm];
            float4 a1 = *(const float4*)&As[kk][tm + 4];
            float4 b0 = *(const float4*)&Bs[kk][tn];
            float4 b1 = *(const float4*)&Bs[kk][tn + 4];
            float a[TM] = {a0.x, a0.y, a0.z, a0.w, a1.x, a1.y, a1.z, a1.w};
            float b[TN] = {b0.x, b0.y, b0.z, b0.w, b1.x, b1.y, b1.z, b1.w};
#pragma unroll
            for (int i = 0; i < TM; i++)
#pragma unroll
                for (int j = 0; j < TN; j++) acc[i][j] = fmaf(a[i], b[j], acc[i][j]);
        }
        __syncthreads();
    }

#pragma unroll
    for (int i = 0; i < TM; i++) {
        const int row = m0 + tm + i;
#pragma unroll
        for (int j = 0; j < TN; j++) {
            const int col = n0 + tn + j;
            if (col >= N) continue;
            float v = acc[i][j];
            if (MODE == EP_SPLIT_SILU) {
                v += bias[col];
                if (col < Esplit)
                    C[(size_t)row * Esplit + col] = v;
                else
                    out2[(size_t)row * Esplit + (col - Esplit)] = silu_f(v);
            } else if (MODE == EP_SOFTPLUS) {
                C[(size_t)row * ldc + col] = softplus_f(v + bias[col]);
            } else if (MODE == EP_BIAS) {
                C[(size_t)row * ldc + col] = v + bias[col];
            } else {
                C[(size_t)row * ldc + col] = v;
            }
        }
    }
}

// Depthwise causal conv (K=4) along L + bias + SiLU.
__global__ __launch_bounds__(256) void conv_silu(
    const float* __restrict__ xin, const float* __restrict__ w,
    const float* __restrict__ cb, float* __restrict__ xo,
    int Ln, int En, size_t total)
{
    for (size_t idx = (size_t)blockIdx.x * 256 + threadIdx.x; idx < total;
         idx += (size_t)gridDim.x * 256) {
        const int e = (int)(idx % En);
        const size_t row = idx / En;
        const int l = (int)(row % Ln);
        float acc = cb[e];
        const float* wp = w + (size_t)e * 4;
#pragma unroll
        for (int k = 0; k < 4; k++) {
            const int li = l - 3 + k;
            if (li >= 0) acc = fmaf(wp[k], xin[(row - 3 + k) * (size_t)En + e], acc);
        }
        xo[idx] = silu_f(acc);
    }
}

// ---- Chunked parallel selective scan ----
// Pass 1: thread = (b, chunk, e); 16 states in regs.
// Emits P[c][b][e][n] = exp(An * sum(d)) and S = local end state (h from 0).
__global__ __launch_bounds__(256) void scan_pass1(
    const float* __restrict__ delta, const float* __restrict__ u,
    const float* __restrict__ proj, const float* __restrict__ A_log,
    float* __restrict__ Pbuf, float* __restrict__ Sbuf)
{
    __shared__ float sB[ST * SN];
    const int tid = threadIdx.x;
    const int eb = blockIdx.x & 7;          // E/256 = 8
    const int c  = (blockIdx.x >> 3) & (SC - 1);
    const int b  = blockIdx.x >> 9;
    const int e  = eb * 256 + tid;
    const size_t row0 = (size_t)b * SL + c * ST;

    for (int i = tid; i < ST * SN; i += 256) {
        const int tl = i >> 4, n = i & 15;
        sB[i] = proj[(row0 + tl) * 160 + 128 + n];
    }
    __syncthreads();

    float An[SN], h[SN];
    {
        const float4* Ap = (const float4*)(A_log + (size_t)e * SN);
#pragma unroll
        for (int q = 0; q < 4; q++) {
            float4 v = Ap[q];
            An[q * 4 + 0] = -expf(v.x);
            An[q * 4 + 1] = -expf(v.y);
            An[q * 4 + 2] = -expf(v.z);
            An[q * 4 + 3] = -expf(v.w);
        }
    }
#pragma unroll
    for (int n = 0; n < SN; n++) h[n] = 0.f;

    float dsum = 0.f;
    size_t idx = row0 * SE + e;
    float d = delta[idx], uu = u[idx];
    for (int tl = 0; tl < ST; tl++) {
        float dn = 0.f, un = 0.f;
        if (tl + 1 < ST) { dn = delta[idx + SE]; un = u[idx + SE]; }
        const float du = d * uu;
        dsum += d;
#pragma unroll
        for (int n = 0; n < SN; n++) {
            const float dA = __expf(d * An[n]);
            h[n] = fmaf(dA, h[n], du * sB[tl * SN + n]);
        }
        d = dn; uu = un; idx += SE;
    }

    const size_t ob = ((((size_t)c * SB) + b) * SE + e) * SN;
#pragma unroll
    for (int q = 0; q < 4; q++) {
        float4 pv, sv;
        pv.x = __expf(An[q * 4 + 0] * dsum); sv.x = h[q * 4 + 0];
        pv.y = __expf(An[q * 4 + 1] * dsum); sv.y = h[q * 4 + 1];
        pv.z = __expf(An[q * 4 + 2] * dsum); sv.z = h[q * 4 + 2];
        pv.w = __expf(An[q * 4 + 3] * dsum); sv.w = h[q * 4 + 3];
        *(float4*)(Pbuf + ob + q * 4) = pv;
        *(float4*)(Sbuf + ob + q * 4) = sv;
    }
}

// Pass 2: thread = (b,e,n); sequential combine over chunks -> hinit[c][b][e][n].
__global__ __launch_bounds__(256) void scan_pass2(
    const float* __restrict__ Pbuf, const float* __restrict__ Sbuf,
    float* __restrict__ hinit)
{
    const size_t g = (size_t)blockIdx.x * 256 + threadIdx.x;  // < B*E*N
    const size_t stride = (size_t)SB * SE * SN;
    float h = 0.f;
    float P = Pbuf[g], S = Sbuf[g];
    for (int c = 0; c < SC; c++) {
        float Pn = 0.f, Sn = 0.f;
        if (c + 1 < SC) {
            Pn = Pbuf[(c + 1) * stride + g];
            Sn = Sbuf[(c + 1) * stride + g];
        }
        hinit[c * stride + g] = h;
        h = fmaf(P, h, S);
        P = Pn; S = Sn;
    }
}

// Pass 3: recompute local scan with correct initial state; y = sum(h*C); fuse gate.
__global__ __launch_bounds__(256) void scan_pass3(
    const float* __restrict__ delta, const float* __restrict__ u,
    const float* __restrict__ proj, const float* __restrict__ A_log,
    const float* __restrict__ Dp, const float* __restrict__ xr,
    const float* __restrict__ hinit, float* __restrict__ yg)
{
    __shared__ float sB[ST * SN];
    __shared__ float sC[ST * SN];
    const int tid = threadIdx.x;
    const int eb = blockIdx.x & 7;
    const int c  = (blockIdx.x >> 3) & (SC - 1);
    const int b  = blockIdx.x >> 9;
    const int e  = eb * 256 + tid;
    const size_t row0 = (size_t)b * SL + c * ST;

    for (int i = tid; i < ST * SN; i += 256) {
        const int tl = i >> 4, n = i & 15;
        sB[i] = proj[(row0 + tl) * 160 + 128 + n];
        sC[i] = proj[(row0 + tl) * 160 + 144 + n];
    }
    __syncthreads();

    float An[SN], h[SN];
    {
        const float4* Ap = (const float4*)(A_log + (size_t)e * SN);
#pragma unroll
        for (int q = 0; q < 4; q++) {
            float4 v = Ap[q];
            An[q * 4 + 0] = -expf(v.x);
            An[q * 4 + 1] = -expf(v.y);
            An[q * 4 + 2] = -expf(v.z);
            An[q * 4 + 3] = -expf(v.w);
        }
    }
    {
        const size_t ib = ((((size_t)c * SB) + b) * SE + e) * SN;
#pragma unroll
        for (int q = 0; q < 4; q++) {
            float4 v = *(const float4*)(hinit + ib + q * 4);
            h[q * 4 + 0] = v.x; h[q * 4 + 1] = v.y;
            h[q * 4 + 2] = v.z; h[q * 4 + 3] = v.w;
        }
    }
    const float De = Dp[e];

    size_t idx = row0 * SE + e;
    float d = delta[idx], uu = u[idx], g = xr[idx];
    for (int tl = 0; tl < ST; tl++) {
        float dn = 0.f, un = 0.f, gn = 0.f;
        if (tl + 1 < ST) {
            dn = delta[idx + SE]; un = u[idx + SE]; gn = xr[idx + SE];
        }
        const float du = d * uu;
        float y = 0.f;
#pragma unroll
        for (int n = 0; n < SN; n++) {
            const float dA = __expf(d * An[n]);
            h[n] = fmaf(dA, h[n], du * sB[tl * SN + n]);
            y = fmaf(h[n], sC[tl * SN + n], y);
        }
        yg[idx] = (y + uu * De) * g;
        d = dn; uu = un; g = gn; idx += SE;
    }
}

extern "C" void kernel_launch(void* const* d_in, const int* in_sizes, int n_in,
                              void* d_out, int out_size, void* d_ws, size_t ws_size,
                              hipStream_t stream)
{
    const int Bc = 2, Lc = 2048, Hc = 1024, Ec = 2048;
    const int M = Bc * Lc;      // 4096
    const int PN = 160;
    const int DTR = 128;

    const float* x        = (const float*)d_in[0];
    const float* W_in     = (const float*)d_in[1];
    const float* b_in     = (const float*)d_in[2];
    const float* conv_w   = (const float*)d_in[3];
    const float* conv_b   = (const float*)d_in[4];
    const float* x_proj_w = (const float*)d_in[5];
    const float* dt_proj_w= (const float*)d_in[6];
    const float* dt_bias  = (const float*)d_in[7];
    const float* A_log    = (const float*)d_in[8];
    const float* D_param  = (const float*)d_in[9];
    const float* W_out    = (const float*)d_in[10];
    const float* b_out    = (const float*)d_in[11];
    float* out = (float*)d_out;

    float* ws = (float*)d_ws;
    const size_t ME = (size_t)M * Ec;          // 8,388,608 floats
    const size_t PS = (size_t)SB * SE * SC * SN; // 4,194,304 floats

    float* xc_raw = ws;                 // M*E   (dead after conv; then P,S; then yg)
    float* xr     = xc_raw + ME;        // M*E
    float* xc     = xr + ME;            // M*E
    float* delta  = xc + ME;            // M*E
    float* proj   = delta + ME;         // M*160
    float* hinit  = proj + (size_t)M * PN;  // B*E*SC*SN
    float* Pbuf   = xc_raw;             // overlays dead xc_raw
    float* Sbuf   = xc_raw + PS;
    float* yg     = xc_raw;             // pass3 output overwrites P/S (dead by then)

    // 1) z = x @ W_in + b_in ; split -> xc_raw, silu -> xr
    sgemm_ep<EP_SPLIT_SILU><<<dim3(2 * Ec / BN, M / BM), 256, 0, stream>>>(
        x, Hc, W_in, 2 * Ec, xc_raw, Ec, b_in, xr, M, 2 * Ec, Hc, Ec);

    // 2) depthwise causal conv + bias + silu -> xc
    conv_silu<<<2048, 256, 0, stream>>>(xc_raw, conv_w, conv_b, xc, Lc, Ec, ME);

    // 3) proj = xc @ x_proj_w
    sgemm_ep<EP_PLAIN><<<dim3((PN + BN - 1) / BN, M / BM), 256, 0, stream>>>(
        xc, Ec, x_proj_w, PN, proj, PN, nullptr, nullptr, M, PN, Ec, 0);

    // 4) delta = softplus(dt @ dt_proj_w + dt_bias)
    sgemm_ep<EP_SOFTPLUS><<<dim3(Ec / BN, M / BM), 256, 0, stream>>>(
        proj, PN, dt_proj_w, Ec, delta, Ec, dt_bias, nullptr, M, Ec, DTR, 0);

    // 5) chunked parallel scan
    scan_pass1<<<SB * SC * (SE / 256), 256, 0, stream>>>(
        delta, xc, proj, A_log, Pbuf, Sbuf);
    scan_pass2<<<(SB * SE * SN) / 256, 256, 0, stream>>>(Pbuf, Sbuf, hinit);
    scan_pass3<<<SB * SC * (SE / 256), 256, 0, stream>>>(
        delta, xc, proj, A_log, D_param, xr, hinit, yg);

    // 6) out = yg @ W_out + b_out
    sgemm_ep<EP_BIAS><<<dim3(Hc / BN, M / BM), 256, 0, stream>>>(
        yg, Ec, W_out, Hc, out, Hc, b_out, nullptr, M, Hc, Ec, 0);
}

// Round 3
// 696.901 us; speedup vs baseline: 3.8843x; 1.9440x over previous
//
#include <hip/hip_runtime.h>
#include <cstdint>

#define BM 128
#define BN 128
#define BK 8
#define TM 8
#define TN 8

// scan geometry
#define SL 2048
#define SE 2048
#define SB 2
#define SN 16
#define SC 64
#define ST 32

enum { EP_PLAIN = 0, EP_SPLIT_SILU = 1, EP_SOFTPLUS = 2, EP_BIAS = 3 };

typedef __attribute__((ext_vector_type(8))) short bf16x8;
typedef __attribute__((ext_vector_type(4))) float f32x4;

__device__ __forceinline__ float silu_f(float x) { return x / (1.f + __expf(-x)); }
__device__ __forceinline__ float softplus_f(float x) {
    return (x > 20.f) ? x : log1pf(__expf(x));
}
__device__ __forceinline__ ushort f2bf(float f) {
    union { float f; unsigned u; } a; a.f = f;
    unsigned r = a.u + 0x7fff + ((a.u >> 16) & 1);
    return (ushort)(r >> 16);
}
__device__ __forceinline__ void gload16(const void* g, void* l) {
    __builtin_amdgcn_global_load_lds(
        (const __attribute__((address_space(1))) unsigned int*)g,
        (__attribute__((address_space(3))) unsigned int*)l, 16, 0, 0);
}

// ---- bf16 MFMA GEMM: C(MxN) = A(MxK) * Bt(NxK)^T, fp32 epilogue ----
template <int MODE>
__global__ __launch_bounds__(256) void hgemm_bt(
    const ushort* __restrict__ A, const ushort* __restrict__ Bt,
    float* __restrict__ C, const float* __restrict__ bias,
    float* __restrict__ out2, int M, int N, int K, int Esplit)
{
    __shared__ ushort As[128 * 64];
    __shared__ ushort Bs[128 * 64];
    const int tid = threadIdx.x;
    const int w = tid >> 6, l = tid & 63;
    const int wr = w >> 1, wc = w & 1;
    const int m0 = blockIdx.y * 128, n0 = blockIdx.x * 128;
    const int srow = l >> 3;          // 0..7
    const int scol = (l & 7) * 8;     // k elem offset for staging

    f32x4 acc[4][4];
#pragma unroll
    for (int m = 0; m < 4; m++)
#pragma unroll
        for (int n = 0; n < 4; n++) acc[m][n] = (f32x4)(0.f);

    for (int k0 = 0; k0 < K; k0 += 64) {
#pragma unroll
        for (int r = 0; r < 4; r++) {
            const int row = r * 32 + w * 8 + srow;
            gload16(A  + (size_t)(m0 + row) * K + k0 + scol, As + r * 2048 + w * 512);
            gload16(Bt + (size_t)(n0 + row) * K + k0 + scol, Bs + r * 2048 + w * 512);
        }
        __syncthreads();
        const int fr = l & 15, kc = (l >> 4) * 8;
#pragma unroll
        for (int kk = 0; kk < 64; kk += 32) {
            bf16x8 af[4], bfr[4];
#pragma unroll
            for (int m = 0; m < 4; m++)
                af[m] = *(const bf16x8*)&As[(wr * 64 + m * 16 + fr) * 64 + kk + kc];
#pragma unroll
            for (int n = 0; n < 4; n++)
                bfr[n] = *(const bf16x8*)&Bs[(wc * 64 + n * 16 + fr) * 64 + kk + kc];
#pragma unroll
            for (int m = 0; m < 4; m++)
#pragma unroll
                for (int n = 0; n < 4; n++)
                    acc[m][n] = __builtin_amdgcn_mfma_f32_16x16x32_bf16(
                        af[m], bfr[n], acc[m][n], 0, 0, 0);
        }
        __syncthreads();
    }

    const int cr = (l >> 4) * 4, cc = l & 15;
#pragma unroll
    for (int m = 0; m < 4; m++) {
#pragma unroll
        for (int j = 0; j < 4; j++) {
            const int row = m0 + wr * 64 + m * 16 + cr + j;
#pragma unroll
            for (int n = 0; n < 4; n++) {
                const int col = n0 + wc * 64 + n * 16 + cc;
                float v = acc[m][n][j];
                if (MODE == EP_SPLIT_SILU) {
                    v += bias[col];
                    if (col < Esplit)
                        C[(size_t)row * Esplit + col] = v;
                    else
                        out2[(size_t)row * Esplit + (col - Esplit)] = silu_f(v);
                } else {  // EP_BIAS
                    C[(size_t)row * N + col] = v + bias[col];
                }
            }
        }
    }
}

// fp32 -> bf16 copy (vectorized)
__global__ __launch_bounds__(256) void f2bf_vec(
    const float* __restrict__ in, ushort* __restrict__ out, size_t n4)
{
    for (size_t i = (size_t)blockIdx.x * 256 + threadIdx.x; i < n4;
         i += (size_t)gridDim.x * 256) {
        float4 v = ((const float4*)in)[i];
        ushort4 o;
        o.x = f2bf(v.x); o.y = f2bf(v.y); o.z = f2bf(v.z); o.w = f2bf(v.w);
        ((ushort4*)out)[i] = o;
    }
}

// W (R x Ccols) fp32 -> Wt (Ccols x R) bf16, tiled transpose
__global__ __launch_bounds__(256) void f2bf_transpose(
    const float* __restrict__ W, ushort* __restrict__ Wt, int R, int Ccols)
{
    __shared__ float tile[32][33];
    const int bc = blockIdx.x * 32, br = blockIdx.y * 32;
    const int tx = threadIdx.x & 31, ty = threadIdx.x >> 5;
    for (int i = ty; i < 32; i += 8)
        tile[i][tx] = W[(size_t)(br + i) * Ccols + bc + tx];
    __syncthreads();
    for (int i = ty; i < 32; i += 8)
        Wt[(size_t)(bc + i) * R + br + tx] = f2bf(tile[tx][i]);
}

// ---- fp32 SGEMM (small GEMMs: x_proj, dt_proj) ----
template <int MODE>
__global__ __launch_bounds__(256) void sgemm_ep(
    const float* __restrict__ A, int lda,
    const float* __restrict__ B, int ldb,
    float* __restrict__ C, int ldc,
    const float* __restrict__ bias,
    float* __restrict__ out2,
    int M, int N, int K, int Esplit)
{
    __shared__ float As[BK][BM];
    __shared__ float Bs[BK][BN];
    const int tid = threadIdx.x;
    const int m0 = blockIdx.y * BM;
    const int n0 = blockIdx.x * BN;
    const int ar = tid >> 1, ac = (tid & 1) * 4;
    const int br = tid >> 5, bc = (tid & 31) * 4;
    const int tm = (tid >> 4) * TM;
    const int tn = (tid & 15) * TN;

    float acc[TM][TN];
#pragma unroll
    for (int i = 0; i < TM; i++)
#pragma unroll
        for (int j = 0; j < TN; j++) acc[i][j] = 0.f;

    for (int k0 = 0; k0 < K; k0 += BK) {
        const float* Ap = A + (size_t)(m0 + ar) * lda + (k0 + ac);
        float4 av = *(const float4*)Ap;
        As[ac + 0][ar] = av.x;
        As[ac + 1][ar] = av.y;
        As[ac + 2][ar] = av.z;
        As[ac + 3][ar] = av.w;
        float4 bv = make_float4(0.f, 0.f, 0.f, 0.f);
        const int gc = n0 + bc;
        if (gc < N) bv = *(const float4*)(B + (size_t)(k0 + br) * ldb + gc);
        *(float4*)&Bs[br][bc] = bv;
        __syncthreads();
#pragma unroll
        for (int kk = 0; kk < BK; kk++) {
            float4 a0 = *(const float4*)&As[kk][tm];
            float4 a1 = *(const float4*)&As[kk][tm + 4];
            float4 b0 = *(const float4*)&Bs[kk][tn];
            float4 b1 = *(const float4*)&Bs[kk][tn + 4];
            float a[TM] = {a0.x, a0.y, a0.z, a0.w, a1.x, a1.y, a1.z, a1.w};
            float b[TN] = {b0.x, b0.y, b0.z, b0.w, b1.x, b1.y, b1.z, b1.w};
#pragma unroll
            for (int i = 0; i < TM; i++)
#pragma unroll
                for (int j = 0; j < TN; j++) acc[i][j] = fmaf(a[i], b[j], acc[i][j]);
        }
        __syncthreads();
    }

#pragma unroll
    for (int i = 0; i < TM; i++) {
        const int row = m0 + tm + i;
#pragma unroll
        for (int j = 0; j < TN; j++) {
            const int col = n0 + tn + j;
            if (col >= N) continue;
            float v = acc[i][j];
            if (MODE == EP_SOFTPLUS) {
                C[(size_t)row * ldc + col] = softplus_f(v + bias[col]);
            } else {
                C[(size_t)row * ldc + col] = v;
            }
        }
    }
}

// Depthwise causal conv (K=4) along L + bias + SiLU.
__global__ __launch_bounds__(256) void conv_silu(
    const float* __restrict__ xin, const float* __restrict__ w,
    const float* __restrict__ cb, float* __restrict__ xo,
    int Ln, int En, size_t total)
{
    for (size_t idx = (size_t)blockIdx.x * 256 + threadIdx.x; idx < total;
         idx += (size_t)gridDim.x * 256) {
        const int e = (int)(idx % En);
        const size_t row = idx / En;
        const int l = (int)(row % Ln);
        float acc = cb[e];
        const float* wp = w + (size_t)e * 4;
#pragma unroll
        for (int k = 0; k < 4; k++) {
            const int li = l - 3 + k;
            if (li >= 0) acc = fmaf(wp[k], xin[(row - 3 + k) * (size_t)En + e], acc);
        }
        xo[idx] = silu_f(acc);
    }
}

// ---- Chunked parallel selective scan ----
__global__ __launch_bounds__(256) void scan_pass1(
    const float* __restrict__ delta, const float* __restrict__ u,
    const float* __restrict__ proj, const float* __restrict__ A_log,
    float* __restrict__ Pbuf, float* __restrict__ Sbuf)
{
    __shared__ float sB[ST * SN];
    const int tid = threadIdx.x;
    const int eb = blockIdx.x & 7;
    const int c  = (blockIdx.x >> 3) & (SC - 1);
    const int b  = blockIdx.x >> 9;
    const int e  = eb * 256 + tid;
    const size_t row0 = (size_t)b * SL + c * ST;

    for (int i = tid; i < ST * SN; i += 256) {
        const int tl = i >> 4, n = i & 15;
        sB[i] = proj[(row0 + tl) * 160 + 128 + n];
    }
    __syncthreads();

    float An[SN], h[SN];
    {
        const float4* Ap = (const float4*)(A_log + (size_t)e * SN);
#pragma unroll
        for (int q = 0; q < 4; q++) {
            float4 v = Ap[q];
            An[q * 4 + 0] = -expf(v.x);
            An[q * 4 + 1] = -expf(v.y);
            An[q * 4 + 2] = -expf(v.z);
            An[q * 4 + 3] = -expf(v.w);
        }
    }
#pragma unroll
    for (int n = 0; n < SN; n++) h[n] = 0.f;

    float dsum = 0.f;
    size_t idx = row0 * SE + e;
    float d = delta[idx], uu = u[idx];
    for (int tl = 0; tl < ST; tl++) {
        float dn = 0.f, un = 0.f;
        if (tl + 1 < ST) { dn = delta[idx + SE]; un = u[idx + SE]; }
        const float du = d * uu;
        dsum += d;
#pragma unroll
        for (int n = 0; n < SN; n++) {
            const float dA = __expf(d * An[n]);
            h[n] = fmaf(dA, h[n], du * sB[tl * SN + n]);
        }
        d = dn; uu = un; idx += SE;
    }

    const size_t ob = ((((size_t)c * SB) + b) * SE + e) * SN;
#pragma unroll
    for (int q = 0; q < 4; q++) {
        float4 pv, sv;
        pv.x = __expf(An[q * 4 + 0] * dsum); sv.x = h[q * 4 + 0];
        pv.y = __expf(An[q * 4 + 1] * dsum); sv.y = h[q * 4 + 1];
        pv.z = __expf(An[q * 4 + 2] * dsum); sv.z = h[q * 4 + 2];
        pv.w = __expf(An[q * 4 + 3] * dsum); sv.w = h[q * 4 + 3];
        *(float4*)(Pbuf + ob + q * 4) = pv;
        *(float4*)(Sbuf + ob + q * 4) = sv;
    }
}

__global__ __launch_bounds__(256) void scan_pass2(
    const float* __restrict__ Pbuf, const float* __restrict__ Sbuf,
    float* __restrict__ hinit)
{
    const size_t g = (size_t)blockIdx.x * 256 + threadIdx.x;
    const size_t stride = (size_t)SB * SE * SN;
    float h = 0.f;
    float P = Pbuf[g], S = Sbuf[g];
    for (int c = 0; c < SC; c++) {
        float Pn = 0.f, Sn = 0.f;
        if (c + 1 < SC) {
            Pn = Pbuf[(c + 1) * stride + g];
            Sn = Sbuf[(c + 1) * stride + g];
        }
        hinit[c * stride + g] = h;
        h = fmaf(P, h, S);
        P = Pn; S = Sn;
    }
}

// Pass 3: local scan with correct init; y=sum(h*C); gate; write bf16 for GEMM6.
__global__ __launch_bounds__(256) void scan_pass3(
    const float* __restrict__ delta, const float* __restrict__ u,
    const float* __restrict__ proj, const float* __restrict__ A_log,
    const float* __restrict__ Dp, const float* __restrict__ xr,
    const float* __restrict__ hinit, ushort* __restrict__ yg)
{
    __shared__ float sB[ST * SN];
    __shared__ float sC[ST * SN];
    const int tid = threadIdx.x;
    const int eb = blockIdx.x & 7;
    const int c  = (blockIdx.x >> 3) & (SC - 1);
    const int b  = blockIdx.x >> 9;
    const int e  = eb * 256 + tid;
    const size_t row0 = (size_t)b * SL + c * ST;

    for (int i = tid; i < ST * SN; i += 256) {
        const int tl = i >> 4, n = i & 15;
        sB[i] = proj[(row0 + tl) * 160 + 128 + n];
        sC[i] = proj[(row0 + tl) * 160 + 144 + n];
    }
    __syncthreads();

    float An[SN], h[SN];
    {
        const float4* Ap = (const float4*)(A_log + (size_t)e * SN);
#pragma unroll
        for (int q = 0; q < 4; q++) {
            float4 v = Ap[q];
            An[q * 4 + 0] = -expf(v.x);
            An[q * 4 + 1] = -expf(v.y);
            An[q * 4 + 2] = -expf(v.z);
            An[q * 4 + 3] = -expf(v.w);
        }
    }
    {
        const size_t ib = ((((size_t)c * SB) + b) * SE + e) * SN;
#pragma unroll
        for (int q = 0; q < 4; q++) {
            float4 v = *(const float4*)(hinit + ib + q * 4);
            h[q * 4 + 0] = v.x; h[q * 4 + 1] = v.y;
            h[q * 4 + 2] = v.z; h[q * 4 + 3] = v.w;
        }
    }
    const float De = Dp[e];

    size_t idx = row0 * SE + e;
    float d = delta[idx], uu = u[idx], g = xr[idx];
    for (int tl = 0; tl < ST; tl++) {
        float dn = 0.f, un = 0.f, gn = 0.f;
        if (tl + 1 < ST) {
            dn = delta[idx + SE]; un = u[idx + SE]; gn = xr[idx + SE];
        }
        const float du = d * uu;
        float y = 0.f;
#pragma unroll
        for (int n = 0; n < SN; n++) {
            const float dA = __expf(d * An[n]);
            h[n] = fmaf(dA, h[n], du * sB[tl * SN + n]);
            y = fmaf(h[n], sC[tl * SN + n], y);
        }
        yg[idx] = f2bf((y + uu * De) * g);
        d = dn; uu = un; g = gn; idx += SE;
    }
}

extern "C" void kernel_launch(void* const* d_in, const int* in_sizes, int n_in,
                              void* d_out, int out_size, void* d_ws, size_t ws_size,
                              hipStream_t stream)
{
    const int Bc = 2, Lc = 2048, Hc = 1024, Ec = 2048;
    const int M = Bc * Lc;
    const int PN = 160;
    const int DTR = 128;

    const float* x        = (const float*)d_in[0];
    const float* W_in     = (const float*)d_in[1];
    const float* b_in     = (const float*)d_in[2];
    const float* conv_w   = (const float*)d_in[3];
    const float* conv_b   = (const float*)d_in[4];
    const float* x_proj_w = (const float*)d_in[5];
    const float* dt_proj_w= (const float*)d_in[6];
    const float* dt_bias  = (const float*)d_in[7];
    const float* A_log    = (const float*)d_in[8];
    const float* D_param  = (const float*)d_in[9];
    const float* W_out    = (const float*)d_in[10];
    const float* b_out    = (const float*)d_in[11];
    float* out = (float*)d_out;

    float* ws = (float*)d_ws;
    const size_t ME = (size_t)M * Ec;            // 8,388,608 floats (33.5 MB)
    const size_t PS = (size_t)SB * SE * SC * SN; // 4,194,304 floats

    float* xc_raw = ws;                  // region0: GEMM1 out / P,S / ygbf
    float* xr     = xc_raw + ME;
    float* xc     = xr + ME;             // region2: W_in_t early, then conv out
    float* delta  = xc + ME;             // region3: xbf early, delta, then W_out_t
    float* proj   = delta + ME;
    float* hinit  = proj + (size_t)M * PN;

    ushort* xbf    = (ushort*)delta;         // 4M ushorts, dead before delta written
    ushort* W_in_t = (ushort*)xc;            // 4M ushorts, dead before xc written
    float*  Pbuf   = xc_raw;
    float*  Sbuf   = xc_raw + PS;
    ushort* ygbf   = (ushort*)xc_raw;        // pass3 out, overlays dead Pbuf
    ushort* W_out_t= (ushort*)delta;         // written after pass3 (delta dead)

    // 0a) x -> bf16
    f2bf_vec<<<1024, 256, 0, stream>>>(x, xbf, (size_t)M * Hc / 4);
    // 0b) W_in (H x 2E) -> bf16 (2E x H)
    f2bf_transpose<<<dim3(2 * Ec / 32, Hc / 32), 256, 0, stream>>>(
        W_in, W_in_t, Hc, 2 * Ec);

    // 1) z = x @ W_in + b_in ; split -> xc_raw (fp32), silu -> xr (fp32)
    hgemm_bt<EP_SPLIT_SILU><<<dim3(2 * Ec / 128, M / 128), 256, 0, stream>>>(
        xbf, W_in_t, xc_raw, b_in, xr, M, 2 * Ec, Hc, Ec);

    // 2) depthwise causal conv + bias + silu -> xc
    conv_silu<<<2048, 256, 0, stream>>>(xc_raw, conv_w, conv_b, xc, Lc, Ec, ME);

    // 3) proj = xc @ x_proj_w (fp32)
    sgemm_ep<EP_PLAIN><<<dim3((PN + BN - 1) / BN, M / BM), 256, 0, stream>>>(
        xc, Ec, x_proj_w, PN, proj, PN, nullptr, nullptr, M, PN, Ec, 0);

    // 4) delta = softplus(dt @ dt_proj_w + dt_bias) (fp32)
    sgemm_ep<EP_SOFTPLUS><<<dim3(Ec / BN, M / BM), 256, 0, stream>>>(
        proj, PN, dt_proj_w, Ec, delta, Ec, dt_bias, nullptr, M, Ec, DTR, 0);

    // 5) chunked parallel scan; pass3 emits bf16 yg
    scan_pass1<<<SB * SC * (SE / 256), 256, 0, stream>>>(
        delta, xc, proj, A_log, Pbuf, Sbuf);
    scan_pass2<<<(SB * SE * SN) / 256, 256, 0, stream>>>(Pbuf, Sbuf, hinit);
    scan_pass3<<<SB * SC * (SE / 256), 256, 0, stream>>>(
        delta, xc, proj, A_log, D_param, xr, hinit, ygbf);

    // 5b) W_out (E x H) -> bf16 (H x E)   (delta region dead now)
    f2bf_transpose<<<dim3(Hc / 32, Ec / 32), 256, 0, stream>>>(
        W_out, W_out_t, Ec, Hc);

    // 6) out = yg @ W_out + b_out
    hgemm_bt<EP_BIAS><<<dim3(Hc / 128, M / 128), 256, 0, stream>>>(
        ygbf, W_out_t, out, b_out, nullptr, M, Hc, Ec, 0);
}

// Round 4
// 382.027 us; speedup vs baseline: 7.0858x; 1.8242x over previous
//
#include <hip/hip_runtime.h>
#include <cstdint>

// scan geometry
#define SL 2048
#define SE 2048
#define SB 2
#define SN 16
#define SC 64
#define ST 32

enum { EP_PLAIN = 0, EP_SPLIT_SILU = 1, EP_SOFTPLUS = 2, EP_BIAS = 3 };

typedef __attribute__((ext_vector_type(8))) short bf16x8;
typedef __attribute__((ext_vector_type(4))) float f32x4;

__device__ __forceinline__ float silu_f(float x) { return x / (1.f + __expf(-x)); }
__device__ __forceinline__ float softplus_f(float x) {
    return (x > 20.f) ? x : log1pf(__expf(x));
}
__device__ __forceinline__ ushort f2bf(float f) {
    union { float f; unsigned u; } a; a.f = f;
    unsigned r = a.u + 0x7fff + ((a.u >> 16) & 1);
    return (ushort)(r >> 16);
}
__device__ __forceinline__ void gload16(const void* g, void* l) {
    __builtin_amdgcn_global_load_lds(
        (const __attribute__((address_space(1))) unsigned int*)g,
        (__attribute__((address_space(3))) unsigned int*)l, 16, 0, 0);
}

// ---- bf16 MFMA GEMM: C(MxN) = A(MxK) * Bt(NxK)^T, fp32 epilogue ----
template <int MODE>
__global__ __launch_bounds__(256) void hgemm_bt(
    const ushort* __restrict__ A, const ushort* __restrict__ Bt,
    float* __restrict__ C, const float* __restrict__ bias,
    float* __restrict__ out2, int M, int N, int K, int Esplit)
{
    __shared__ ushort As[128 * 64];
    __shared__ ushort Bs[128 * 64];
    const int tid = threadIdx.x;
    const int w = tid >> 6, l = tid & 63;
    const int wr = w >> 1, wc = w & 1;
    const int m0 = blockIdx.y * 128, n0 = blockIdx.x * 128;
    const int srow = l >> 3;
    const int scol = (l & 7) * 8;

    f32x4 acc[4][4];
#pragma unroll
    for (int m = 0; m < 4; m++)
#pragma unroll
        for (int n = 0; n < 4; n++) acc[m][n] = (f32x4)(0.f);

    for (int k0 = 0; k0 < K; k0 += 64) {
#pragma unroll
        for (int r = 0; r < 4; r++) {
            const int row = r * 32 + w * 8 + srow;
            gload16(A  + (size_t)(m0 + row) * K + k0 + scol, As + r * 2048 + w * 512);
            gload16(Bt + (size_t)(n0 + row) * K + k0 + scol, Bs + r * 2048 + w * 512);
        }
        __syncthreads();
        const int fr = l & 15, kc = (l >> 4) * 8;
#pragma unroll
        for (int kk = 0; kk < 64; kk += 32) {
            bf16x8 af[4], bfr[4];
#pragma unroll
            for (int m = 0; m < 4; m++)
                af[m] = *(const bf16x8*)&As[(wr * 64 + m * 16 + fr) * 64 + kk + kc];
#pragma unroll
            for (int n = 0; n < 4; n++)
                bfr[n] = *(const bf16x8*)&Bs[(wc * 64 + n * 16 + fr) * 64 + kk + kc];
#pragma unroll
            for (int m = 0; m < 4; m++)
#pragma unroll
                for (int n = 0; n < 4; n++)
                    acc[m][n] = __builtin_amdgcn_mfma_f32_16x16x32_bf16(
                        af[m], bfr[n], acc[m][n], 0, 0, 0);
        }
        __syncthreads();
    }

    const int cr = (l >> 4) * 4, cc = l & 15;
#pragma unroll
    for (int m = 0; m < 4; m++) {
#pragma unroll
        for (int j = 0; j < 4; j++) {
            const int row = m0 + wr * 64 + m * 16 + cr + j;
#pragma unroll
            for (int n = 0; n < 4; n++) {
                const int col = n0 + wc * 64 + n * 16 + cc;
                float v = acc[m][n][j];
                if (MODE == EP_SPLIT_SILU) {
                    v += bias[col];
                    if (col < Esplit)
                        C[(size_t)row * Esplit + col] = v;
                    else
                        out2[(size_t)row * Esplit + (col - Esplit)] = silu_f(v);
                } else if (MODE == EP_SOFTPLUS) {
                    C[(size_t)row * N + col] = softplus_f(v + bias[col]);
                } else {  // EP_BIAS
                    C[(size_t)row * N + col] = v + bias[col];
                }
            }
        }
    }
}

// ---- GEMM3 split-K partial: Pp[z] += A(MxK slice) * Bt(NxK)^T, N masked ----
__global__ __launch_bounds__(256) void hgemm3_partial(
    const ushort* __restrict__ A, const ushort* __restrict__ Bt,
    float* __restrict__ Pp, int M, int N, int K, int KS)
{
    __shared__ ushort As[128 * 64];
    __shared__ ushort Bs[128 * 64];
    const int tid = threadIdx.x;
    const int w = tid >> 6, l = tid & 63;
    const int wr = w >> 1, wc = w & 1;
    const int m0 = blockIdx.y * 128, n0 = blockIdx.x * 128;
    const int z = blockIdx.z;
    const int srow = l >> 3;
    const int scol = (l & 7) * 8;

    f32x4 acc[4][4];
#pragma unroll
    for (int m = 0; m < 4; m++)
#pragma unroll
        for (int n = 0; n < 4; n++) acc[m][n] = (f32x4)(0.f);

    const int kbeg = z * KS, kend = kbeg + KS;
    for (int k0 = kbeg; k0 < kend; k0 += 64) {
#pragma unroll
        for (int r = 0; r < 4; r++) {
            const int row = r * 32 + w * 8 + srow;
            int brow = n0 + row; if (brow > N - 1) brow = N - 1;  // clamp OOB rows
            gload16(A  + (size_t)(m0 + row) * K + k0 + scol, As + r * 2048 + w * 512);
            gload16(Bt + (size_t)brow * K + k0 + scol,       Bs + r * 2048 + w * 512);
        }
        __syncthreads();
        const int fr = l & 15, kc = (l >> 4) * 8;
#pragma unroll
        for (int kk = 0; kk < 64; kk += 32) {
            bf16x8 af[4], bfr[4];
#pragma unroll
            for (int m = 0; m < 4; m++)
                af[m] = *(const bf16x8*)&As[(wr * 64 + m * 16 + fr) * 64 + kk + kc];
#pragma unroll
            for (int n = 0; n < 4; n++)
                bfr[n] = *(const bf16x8*)&Bs[(wc * 64 + n * 16 + fr) * 64 + kk + kc];
#pragma unroll
            for (int m = 0; m < 4; m++)
#pragma unroll
                for (int n = 0; n < 4; n++)
                    acc[m][n] = __builtin_amdgcn_mfma_f32_16x16x32_bf16(
                        af[m], bfr[n], acc[m][n], 0, 0, 0);
        }
        __syncthreads();
    }

    const int cr = (l >> 4) * 4, cc = l & 15;
    float* base = Pp + (size_t)z * M * N;
#pragma unroll
    for (int m = 0; m < 4; m++) {
#pragma unroll
        for (int j = 0; j < 4; j++) {
            const int row = m0 + wr * 64 + m * 16 + cr + j;
#pragma unroll
            for (int n = 0; n < 4; n++) {
                const int col = n0 + wc * 64 + n * 16 + cc;
                if (col < N) base[(size_t)row * N + col] = acc[m][n][j];
            }
        }
    }
}

// Reduce split-K partials -> proj fp32; also emit dt columns (<128) as bf16.
__global__ __launch_bounds__(256) void gemm3_reduce(
    const float* __restrict__ Pp, float* __restrict__ proj,
    ushort* __restrict__ dtbf, int M, int N, int Z)
{
    const size_t g = (size_t)blockIdx.x * 256 + threadIdx.x;
    const size_t tot = (size_t)M * N;
    if (g >= tot) return;
    float s = 0.f;
    for (int z = 0; z < Z; z++) s += Pp[(size_t)z * tot + g];
    proj[g] = s;
    const int col = (int)(g % N);
    if (col < 128) {
        const size_t row = g / N;
        dtbf[row * 128 + col] = f2bf(s);
    }
}

// fp32 -> bf16 copy (vectorized)
__global__ __launch_bounds__(256) void f2bf_vec(
    const float* __restrict__ in, ushort* __restrict__ out, size_t n4)
{
    for (size_t i = (size_t)blockIdx.x * 256 + threadIdx.x; i < n4;
         i += (size_t)gridDim.x * 256) {
        float4 v = ((const float4*)in)[i];
        ushort4 o;
        o.x = f2bf(v.x); o.y = f2bf(v.y); o.z = f2bf(v.z); o.w = f2bf(v.w);
        ((ushort4*)out)[i] = o;
    }
}

// W (R x Ccols) fp32 -> Wt (Ccols x R) bf16, tiled transpose
__global__ __launch_bounds__(256) void f2bf_transpose(
    const float* __restrict__ W, ushort* __restrict__ Wt, int R, int Ccols)
{
    __shared__ float tile[32][33];
    const int bc = blockIdx.x * 32, br = blockIdx.y * 32;
    const int tx = threadIdx.x & 31, ty = threadIdx.x >> 5;
    for (int i = ty; i < 32; i += 8)
        tile[i][tx] = W[(size_t)(br + i) * Ccols + bc + tx];
    __syncthreads();
    for (int i = ty; i < 32; i += 8)
        Wt[(size_t)(bc + i) * R + br + tx] = f2bf(tile[tx][i]);
}

// Depthwise causal conv (K=4) along L + bias + SiLU; fp32 + bf16 outputs.
__global__ __launch_bounds__(256) void conv_silu(
    const float* __restrict__ xin, const float* __restrict__ w,
    const float* __restrict__ cb, float* __restrict__ xo,
    ushort* __restrict__ xobf, int Ln, int En, size_t total)
{
    for (size_t idx = (size_t)blockIdx.x * 256 + threadIdx.x; idx < total;
         idx += (size_t)gridDim.x * 256) {
        const int e = (int)(idx % En);
        const size_t row = idx / En;
        const int l = (int)(row % Ln);
        float acc = cb[e];
        const float* wp = w + (size_t)e * 4;
#pragma unroll
        for (int k = 0; k < 4; k++) {
            const int li = l - 3 + k;
            if (li >= 0) acc = fmaf(wp[k], xin[(row - 3 + k) * (size_t)En + e], acc);
        }
        const float v = silu_f(acc);
        xo[idx] = v;
        xobf[idx] = f2bf(v);
    }
}

// ---- Chunked parallel selective scan ----
__global__ __launch_bounds__(256) void scan_pass1(
    const float* __restrict__ delta, const float* __restrict__ u,
    const float* __restrict__ proj, const float* __restrict__ A_log,
    float* __restrict__ Pbuf, float* __restrict__ Sbuf)
{
    __shared__ float sB[ST * SN];
    const int tid = threadIdx.x;
    const int eb = blockIdx.x & 7;
    const int c  = (blockIdx.x >> 3) & (SC - 1);
    const int b  = blockIdx.x >> 9;
    const int e  = eb * 256 + tid;
    const size_t row0 = (size_t)b * SL + c * ST;

    for (int i = tid; i < ST * SN; i += 256) {
        const int tl = i >> 4, n = i & 15;
        sB[i] = proj[(row0 + tl) * 160 + 128 + n];
    }
    __syncthreads();

    float An[SN], h[SN];
    {
        const float4* Ap = (const float4*)(A_log + (size_t)e * SN);
#pragma unroll
        for (int q = 0; q < 4; q++) {
            float4 v = Ap[q];
            An[q * 4 + 0] = -expf(v.x);
            An[q * 4 + 1] = -expf(v.y);
            An[q * 4 + 2] = -expf(v.z);
            An[q * 4 + 3] = -expf(v.w);
        }
    }
#pragma unroll
    for (int n = 0; n < SN; n++) h[n] = 0.f;

    float dsum = 0.f;
    size_t idx = row0 * SE + e;
    float d = delta[idx], uu = u[idx];
    for (int tl = 0; tl < ST; tl++) {
        float dn = 0.f, un = 0.f;
        if (tl + 1 < ST) { dn = delta[idx + SE]; un = u[idx + SE]; }
        const float du = d * uu;
        dsum += d;
#pragma unroll
        for (int n = 0; n < SN; n++) {
            const float dA = __expf(d * An[n]);
            h[n] = fmaf(dA, h[n], du * sB[tl * SN + n]);
        }
        d = dn; uu = un; idx += SE;
    }

    const size_t ob = ((((size_t)c * SB) + b) * SE + e) * SN;
#pragma unroll
    for (int q = 0; q < 4; q++) {
        float4 pv, sv;
        pv.x = __expf(An[q * 4 + 0] * dsum); sv.x = h[q * 4 + 0];
        pv.y = __expf(An[q * 4 + 1] * dsum); sv.y = h[q * 4 + 1];
        pv.z = __expf(An[q * 4 + 2] * dsum); sv.z = h[q * 4 + 2];
        pv.w = __expf(An[q * 4 + 3] * dsum); sv.w = h[q * 4 + 3];
        *(float4*)(Pbuf + ob + q * 4) = pv;
        *(float4*)(Sbuf + ob + q * 4) = sv;
    }
}

__global__ __launch_bounds__(256) void scan_pass2(
    const float* __restrict__ Pbuf, const float* __restrict__ Sbuf,
    float* __restrict__ hinit)
{
    const size_t g = (size_t)blockIdx.x * 256 + threadIdx.x;
    const size_t stride = (size_t)SB * SE * SN;
    float h = 0.f;
    float P = Pbuf[g], S = Sbuf[g];
    for (int c = 0; c < SC; c++) {
        float Pn = 0.f, Sn = 0.f;
        if (c + 1 < SC) {
            Pn = Pbuf[(c + 1) * stride + g];
            Sn = Sbuf[(c + 1) * stride + g];
        }
        hinit[c * stride + g] = h;
        h = fmaf(P, h, S);
        P = Pn; S = Sn;
    }
}

__global__ __launch_bounds__(256) void scan_pass3(
    const float* __restrict__ delta, const float* __restrict__ u,
    const float* __restrict__ proj, const float* __restrict__ A_log,
    const float* __restrict__ Dp, const float* __restrict__ xr,
    const float* __restrict__ hinit, ushort* __restrict__ yg)
{
    __shared__ float sB[ST * SN];
    __shared__ float sC[ST * SN];
    const int tid = threadIdx.x;
    const int eb = blockIdx.x & 7;
    const int c  = (blockIdx.x >> 3) & (SC - 1);
    const int b  = blockIdx.x >> 9;
    const int e  = eb * 256 + tid;
    const size_t row0 = (size_t)b * SL + c * ST;

    for (int i = tid; i < ST * SN; i += 256) {
        const int tl = i >> 4, n = i & 15;
        sB[i] = proj[(row0 + tl) * 160 + 128 + n];
        sC[i] = proj[(row0 + tl) * 160 + 144 + n];
    }
    __syncthreads();

    float An[SN], h[SN];
    {
        const float4* Ap = (const float4*)(A_log + (size_t)e * SN);
#pragma unroll
        for (int q = 0; q < 4; q++) {
            float4 v = Ap[q];
            An[q * 4 + 0] = -expf(v.x);
            An[q * 4 + 1] = -expf(v.y);
            An[q * 4 + 2] = -expf(v.z);
            An[q * 4 + 3] = -expf(v.w);
        }
    }
    {
        const size_t ib = ((((size_t)c * SB) + b) * SE + e) * SN;
#pragma unroll
        for (int q = 0; q < 4; q++) {
            float4 v = *(const float4*)(hinit + ib + q * 4);
            h[q * 4 + 0] = v.x; h[q * 4 + 1] = v.y;
            h[q * 4 + 2] = v.z; h[q * 4 + 3] = v.w;
        }
    }
    const float De = Dp[e];

    size_t idx = row0 * SE + e;
    float d = delta[idx], uu = u[idx], g = xr[idx];
    for (int tl = 0; tl < ST; tl++) {
        float dn = 0.f, un = 0.f, gn = 0.f;
        if (tl + 1 < ST) {
            dn = delta[idx + SE]; un = u[idx + SE]; gn = xr[idx + SE];
        }
        const float du = d * uu;
        float y = 0.f;
#pragma unroll
        for (int n = 0; n < SN; n++) {
            const float dA = __expf(d * An[n]);
            h[n] = fmaf(dA, h[n], du * sB[tl * SN + n]);
            y = fmaf(h[n], sC[tl * SN + n], y);
        }
        yg[idx] = f2bf((y + uu * De) * g);
        d = dn; uu = un; g = gn; idx += SE;
    }
}

extern "C" void kernel_launch(void* const* d_in, const int* in_sizes, int n_in,
                              void* d_out, int out_size, void* d_ws, size_t ws_size,
                              hipStream_t stream)
{
    const int Bc = 2, Lc = 2048, Hc = 1024, Ec = 2048;
    const int M = Bc * Lc;      // 4096
    const int PN = 160;
    const int SKZ = 8;          // GEMM3 split-K factor

    const float* x        = (const float*)d_in[0];
    const float* W_in     = (const float*)d_in[1];
    const float* b_in     = (const float*)d_in[2];
    const float* conv_w   = (const float*)d_in[3];
    const float* conv_b   = (const float*)d_in[4];
    const float* x_proj_w = (const float*)d_in[5];
    const float* dt_proj_w= (const float*)d_in[6];
    const float* dt_bias  = (const float*)d_in[7];
    const float* A_log    = (const float*)d_in[8];
    const float* D_param  = (const float*)d_in[9];
    const float* W_out    = (const float*)d_in[10];
    const float* b_out    = (const float*)d_in[11];
    float* out = (float*)d_out;

    float* ws = (float*)d_ws;
    const size_t ME = (size_t)M * Ec;            // 8,388,608 floats
    const size_t PS = (size_t)SB * SE * SC * SN; // 4,194,304 floats

    // region map (floats):
    float* xc_raw = ws;                  // region0: GEMM1 out / Pp / P,S / ygbf
    float* xr     = xc_raw + ME;         // region1
    float* xc     = xr + ME;             // region2: W_in_t early, then conv out fp32
    float* delta  = xc + ME;             // region3: xbf, then xc_bf, then delta, then W_out_t
    float* proj   = delta + ME;
    float* hinit  = proj + (size_t)M * PN;  // also hosts xpw_t/dtw_t/dtbf pre-pass2

    ushort* xbf    = (ushort*)delta;         // dead after GEMM1
    ushort* W_in_t = (ushort*)xc;            // dead after GEMM1
    ushort* xc_bf  = (ushort*)delta;         // conv out bf16; dead after GEMM3 partial
    float*  Pp     = xc_raw;                 // split-K partials (SKZ*M*160 = 5.2M fl)
    ushort* xpw_t  = (ushort*)hinit;                    // 160*2048 = 327,680 us
    ushort* dtw_t  = (ushort*)hinit + 327680;           // 2048*128 = 262,144 us
    ushort* dtbf   = (ushort*)hinit + 327680 + 262144;  // 4096*128 = 524,288 us
    float*  Pbuf   = xc_raw;
    float*  Sbuf   = xc_raw + PS;
    ushort* ygbf   = (ushort*)xc_raw;
    ushort* W_out_t= (ushort*)delta;         // after pass3 (delta dead)

    // 0) dtype conversions / weight transposes
    f2bf_vec<<<1024, 256, 0, stream>>>(x, xbf, (size_t)M * Hc / 4);
    f2bf_transpose<<<dim3(2 * Ec / 32, Hc / 32), 256, 0, stream>>>(
        W_in, W_in_t, Hc, 2 * Ec);
    f2bf_transpose<<<dim3(PN / 32, Ec / 32), 256, 0, stream>>>(
        x_proj_w, xpw_t, Ec, PN);
    f2bf_transpose<<<dim3(Ec / 32, 128 / 32), 256, 0, stream>>>(
        dt_proj_w, dtw_t, 128, Ec);

    // 1) z = x @ W_in + b_in ; split -> xc_raw (fp32), silu -> xr (fp32)
    hgemm_bt<EP_SPLIT_SILU><<<dim3(2 * Ec / 128, M / 128), 256, 0, stream>>>(
        xbf, W_in_t, xc_raw, b_in, xr, M, 2 * Ec, Hc, Ec);

    // 2) depthwise causal conv + bias + silu -> xc (fp32) + xc_bf (bf16)
    conv_silu<<<2048, 256, 0, stream>>>(xc_raw, conv_w, conv_b, xc, xc_bf, Lc, Ec, ME);

    // 3) proj = xc @ x_proj_w : split-K bf16 MFMA + reduce (emits dt as bf16 too)
    hgemm3_partial<<<dim3(2, M / 128, SKZ), 256, 0, stream>>>(
        xc_bf, xpw_t, Pp, M, PN, Ec, Ec / SKZ);
    gemm3_reduce<<<(M * PN + 255) / 256, 256, 0, stream>>>(
        Pp, proj, dtbf, M, PN, SKZ);

    // 4) delta = softplus(dt @ dt_proj_w + dt_bias) : bf16 MFMA
    hgemm_bt<EP_SOFTPLUS><<<dim3(Ec / 128, M / 128), 256, 0, stream>>>(
        dtbf, dtw_t, delta, dt_bias, nullptr, M, Ec, 128, 0);

    // 5) chunked parallel scan; pass3 emits bf16 yg
    scan_pass1<<<SB * SC * (SE / 256), 256, 0, stream>>>(
        delta, xc, proj, A_log, Pbuf, Sbuf);
    scan_pass2<<<(SB * SE * SN) / 256, 256, 0, stream>>>(Pbuf, Sbuf, hinit);
    scan_pass3<<<SB * SC * (SE / 256), 256, 0, stream>>>(
        delta, xc, proj, A_log, D_param, xr, hinit, ygbf);

    // 5b) W_out (E x H) -> bf16 (H x E)   (delta region dead now)
    f2bf_transpose<<<dim3(Hc / 32, Ec / 32), 256, 0, stream>>>(
        W_out, W_out_t, Ec, Hc);

    // 6) out = yg @ W_out + b_out
    hgemm_bt<EP_BIAS><<<dim3(Hc / 128, M / 128), 256, 0, stream>>>(
        ygbf, W_out_t, out, b_out, nullptr, M, Hc, Ec, 0);
}

// Round 5
// 345.817 us; speedup vs baseline: 7.8277x; 1.1047x over previous
//
#include <hip/hip_runtime.h>
#include <cstdint>

// scan geometry
#define SL 2048
#define SE 2048
#define SB 2
#define SN 16
#define SC 64
#define ST 32

enum { EP_SPLIT_SILU = 1, EP_SOFTPLUS = 2, EP_BIAS = 3, EP_PARTIAL = 4 };

typedef __attribute__((ext_vector_type(8))) short bf16x8;
typedef __attribute__((ext_vector_type(4))) float f32x4;

__device__ __forceinline__ float silu_f(float x) { return x / (1.f + __expf(-x)); }
__device__ __forceinline__ float softplus_f(float x) {
    return (x > 20.f) ? x : log1pf(__expf(x));
}
__device__ __forceinline__ ushort f2bf(float f) {
    union { float f; unsigned u; } a; a.f = f;
    unsigned r = a.u + 0x7fff + ((a.u >> 16) & 1);
    return (ushort)(r >> 16);
}
__device__ __forceinline__ void gload16(const void* g, void* l) {
    __builtin_amdgcn_global_load_lds(
        (const __attribute__((address_space(1))) unsigned int*)g,
        (__attribute__((address_space(3))) unsigned int*)l, 16, 0, 0);
}

// ---- bf16 MFMA GEMM, 128x128 tile, BK=64, double-buffered 2-phase pipeline.
// C(MxN) = A(MxK) * Bt(NxK)^T. blockIdx.z = split-K slice of size KS.
// N may be non-multiple of 128 (B rows clamped, C cols masked).
template <int MODE>
__global__ __launch_bounds__(256, 2) void hgemm2(
    const ushort* __restrict__ A, const ushort* __restrict__ Bt,
    float* __restrict__ C, const float* __restrict__ bias,
    float* __restrict__ out2, int M, int N, int K, int Esplit, int KS)
{
    __shared__ ushort As[2][128 * 64];
    __shared__ ushort Bs[2][128 * 64];
    const int tid = threadIdx.x;
    const int w = tid >> 6, l = tid & 63;
    const int wr = w >> 1, wc = w & 1;
    const int m0 = blockIdx.y * 128, n0 = blockIdx.x * 128;
    const int z = blockIdx.z;
    const int kbeg = z * KS;
    const int nt = KS / 64;
    const int srow = l >> 3, scol = (l & 7) * 8;

    f32x4 acc[4][4];
#pragma unroll
    for (int m = 0; m < 4; m++)
#pragma unroll
        for (int n = 0; n < 4; n++) acc[m][n] = (f32x4)(0.f);

    auto stage = [&](int buf, int t) {
        const int k0 = kbeg + t * 64;
#pragma unroll
        for (int r = 0; r < 4; r++) {
            const int row = r * 32 + w * 8 + srow;
            int brow = n0 + row; if (brow > N - 1) brow = N - 1;  // clamp (N<128k tiles)
            gload16(A + (size_t)(m0 + row) * K + k0 + scol,
                    &As[buf][r * 2048 + w * 512]);
            gload16(Bt + (size_t)brow * K + k0 + scol,
                    &Bs[buf][r * 2048 + w * 512]);
        }
    };

    // prologue: stage tile 0, drain, barrier
    stage(0, 0);
    __syncthreads();

    int cur = 0;
    const int fr = l & 15, kc = (l >> 4) * 8;
    for (int t = 0; t < nt; t++) {
        if (t + 1 < nt) stage(cur ^ 1, t + 1);   // prefetch next tile (other buffer)
#pragma unroll
        for (int kk = 0; kk < 64; kk += 32) {
            bf16x8 af[4], bfr[4];
#pragma unroll
            for (int m = 0; m < 4; m++)
                af[m] = *(const bf16x8*)&As[cur][(wr * 64 + m * 16 + fr) * 64 + kk + kc];
#pragma unroll
            for (int n = 0; n < 4; n++)
                bfr[n] = *(const bf16x8*)&Bs[cur][(wc * 64 + n * 16 + fr) * 64 + kk + kc];
#pragma unroll
            for (int m = 0; m < 4; m++)
#pragma unroll
                for (int n = 0; n < 4; n++)
                    acc[m][n] = __builtin_amdgcn_mfma_f32_16x16x32_bf16(
                        af[m], bfr[n], acc[m][n], 0, 0, 0);
        }
        __syncthreads();   // drains vmcnt(0)+lgkmcnt(0): next buffer ready, reads done
        cur ^= 1;
    }

    const int cr = (l >> 4) * 4, cc = l & 15;
    float* pbase = C + (size_t)z * M * N;   // used by EP_PARTIAL
#pragma unroll
    for (int m = 0; m < 4; m++) {
#pragma unroll
        for (int j = 0; j < 4; j++) {
            const int row = m0 + wr * 64 + m * 16 + cr + j;
#pragma unroll
            for (int n = 0; n < 4; n++) {
                const int col = n0 + wc * 64 + n * 16 + cc;
                float v = acc[m][n][j];
                if (MODE == EP_SPLIT_SILU) {
                    v += bias[col];
                    if (col < Esplit)
                        C[(size_t)row * Esplit + col] = v;
                    else
                        out2[(size_t)row * Esplit + (col - Esplit)] = silu_f(v);
                } else if (MODE == EP_SOFTPLUS) {
                    C[(size_t)row * N + col] = softplus_f(v + bias[col]);
                } else if (MODE == EP_BIAS) {
                    C[(size_t)row * N + col] = v + bias[col];
                } else {  // EP_PARTIAL
                    if (col < N) pbase[(size_t)row * N + col] = v;
                }
            }
        }
    }
}

// Reduce split-K partials -> proj fp32; also emit dt columns (<128) as bf16.
__global__ __launch_bounds__(256) void gemm3_reduce(
    const float* __restrict__ Pp, float* __restrict__ proj,
    ushort* __restrict__ dtbf, int M, int N, int Z)
{
    const size_t g = (size_t)blockIdx.x * 256 + threadIdx.x;
    const size_t tot = (size_t)M * N;
    if (g >= tot) return;
    float s = 0.f;
    for (int z = 0; z < Z; z++) s += Pp[(size_t)z * tot + g];
    proj[g] = s;
    const int col = (int)(g % N);
    if (col < 128) {
        const size_t row = g / N;
        dtbf[row * 128 + col] = f2bf(s);
    }
}

// Reduce GEMM6 split-K(2) partials + bias -> out fp32.
__global__ __launch_bounds__(256) void reduce6(
    const float* __restrict__ Pp, const float* __restrict__ bias,
    float* __restrict__ out, int M, int N)
{
    const size_t g = (size_t)blockIdx.x * 256 + threadIdx.x;
    const size_t tot = (size_t)M * N;
    if (g >= tot) return;
    out[g] = Pp[g] + Pp[tot + g] + bias[g % N];
}

// fp32 -> bf16 copy (vectorized)
__global__ __launch_bounds__(256) void f2bf_vec(
    const float* __restrict__ in, ushort* __restrict__ out, size_t n4)
{
    for (size_t i = (size_t)blockIdx.x * 256 + threadIdx.x; i < n4;
         i += (size_t)gridDim.x * 256) {
        float4 v = ((const float4*)in)[i];
        ushort4 o;
        o.x = f2bf(v.x); o.y = f2bf(v.y); o.z = f2bf(v.z); o.w = f2bf(v.w);
        ((ushort4*)out)[i] = o;
    }
}

// W (R x Ccols) fp32 -> Wt (Ccols x R) bf16, tiled transpose
__global__ __launch_bounds__(256) void f2bf_transpose(
    const float* __restrict__ W, ushort* __restrict__ Wt, int R, int Ccols)
{
    __shared__ float tile[32][33];
    const int bc = blockIdx.x * 32, br = blockIdx.y * 32;
    const int tx = threadIdx.x & 31, ty = threadIdx.x >> 5;
    for (int i = ty; i < 32; i += 8)
        tile[i][tx] = W[(size_t)(br + i) * Ccols + bc + tx];
    __syncthreads();
    for (int i = ty; i < 32; i += 8)
        Wt[(size_t)(bc + i) * R + br + tx] = f2bf(tile[tx][i]);
}

// Depthwise causal conv (K=4) along L + bias + SiLU; 4 channels/thread (float4).
__global__ __launch_bounds__(256) void conv_silu4(
    const float* __restrict__ xin, const float* __restrict__ w,
    const float* __restrict__ cb, float* __restrict__ xo,
    ushort* __restrict__ xobf, int Ln, int En, size_t total4)
{
    const int Eq = En >> 2;
    for (size_t idx = (size_t)blockIdx.x * 256 + threadIdx.x; idx < total4;
         idx += (size_t)gridDim.x * 256) {
        const int e4 = (int)(idx % Eq);
        const size_t row = idx / Eq;
        const int l = (int)(row % Ln);
        float4 acc = ((const float4*)cb)[e4];
        // per-channel tap vectors: w[(4*e4+c)*4 + k]
        const float4 w0 = ((const float4*)w)[e4 * 4 + 0];
        const float4 w1 = ((const float4*)w)[e4 * 4 + 1];
        const float4 w2 = ((const float4*)w)[e4 * 4 + 2];
        const float4 w3 = ((const float4*)w)[e4 * 4 + 3];
        const float wt0[4] = {w0.x, w0.y, w0.z, w0.w};
        const float wt1[4] = {w1.x, w1.y, w1.z, w1.w};
        const float wt2[4] = {w2.x, w2.y, w2.z, w2.w};
        const float wt3[4] = {w3.x, w3.y, w3.z, w3.w};
#pragma unroll
        for (int k = 0; k < 4; k++) {
            if (l - 3 + k >= 0) {
                float4 xv = ((const float4*)xin)[(row - 3 + k) * Eq + e4];
                acc.x = fmaf(wt0[k], xv.x, acc.x);
                acc.y = fmaf(wt1[k], xv.y, acc.y);
                acc.z = fmaf(wt2[k], xv.z, acc.z);
                acc.w = fmaf(wt3[k], xv.w, acc.w);
            }
        }
        float4 v;
        v.x = silu_f(acc.x); v.y = silu_f(acc.y);
        v.z = silu_f(acc.z); v.w = silu_f(acc.w);
        ((float4*)xo)[idx] = v;
        ushort4 o;
        o.x = f2bf(v.x); o.y = f2bf(v.y); o.z = f2bf(v.z); o.w = f2bf(v.w);
        ((ushort4*)xobf)[idx] = o;
    }
}

// ---- Chunked parallel selective scan ----
__global__ __launch_bounds__(256) void scan_pass1(
    const float* __restrict__ delta, const float* __restrict__ u,
    const float* __restrict__ proj, const float* __restrict__ A_log,
    float* __restrict__ Pbuf, float* __restrict__ Sbuf)
{
    __shared__ float sB[ST * SN];
    const int tid = threadIdx.x;
    const int eb = blockIdx.x & 7;
    const int c  = (blockIdx.x >> 3) & (SC - 1);
    const int b  = blockIdx.x >> 9;
    const int e  = eb * 256 + tid;
    const size_t row0 = (size_t)b * SL + c * ST;

    for (int i = tid; i < ST * SN; i += 256) {
        const int tl = i >> 4, n = i & 15;
        sB[i] = proj[(row0 + tl) * 160 + 128 + n];
    }
    __syncthreads();

    float An[SN], h[SN];
    {
        const float4* Ap = (const float4*)(A_log + (size_t)e * SN);
#pragma unroll
        for (int q = 0; q < 4; q++) {
            float4 v = Ap[q];
            An[q * 4 + 0] = -expf(v.x);
            An[q * 4 + 1] = -expf(v.y);
            An[q * 4 + 2] = -expf(v.z);
            An[q * 4 + 3] = -expf(v.w);
        }
    }
#pragma unroll
    for (int n = 0; n < SN; n++) h[n] = 0.f;

    float dsum = 0.f;
    size_t idx = row0 * SE + e;
    float d = delta[idx], uu = u[idx];
    for (int tl = 0; tl < ST; tl++) {
        float dn = 0.f, un = 0.f;
        if (tl + 1 < ST) { dn = delta[idx + SE]; un = u[idx + SE]; }
        const float du = d * uu;
        dsum += d;
#pragma unroll
        for (int n = 0; n < SN; n++) {
            const float dA = __expf(d * An[n]);
            h[n] = fmaf(dA, h[n], du * sB[tl * SN + n]);
        }
        d = dn; uu = un; idx += SE;
    }

    const size_t ob = ((((size_t)c * SB) + b) * SE + e) * SN;
#pragma unroll
    for (int q = 0; q < 4; q++) {
        float4 pv, sv;
        pv.x = __expf(An[q * 4 + 0] * dsum); sv.x = h[q * 4 + 0];
        pv.y = __expf(An[q * 4 + 1] * dsum); sv.y = h[q * 4 + 1];
        pv.z = __expf(An[q * 4 + 2] * dsum); sv.z = h[q * 4 + 2];
        pv.w = __expf(An[q * 4 + 3] * dsum); sv.w = h[q * 4 + 3];
        *(float4*)(Pbuf + ob + q * 4) = pv;
        *(float4*)(Sbuf + ob + q * 4) = sv;
    }
}

__global__ __launch_bounds__(256) void scan_pass2(
    const float* __restrict__ Pbuf, const float* __restrict__ Sbuf,
    float* __restrict__ hinit)
{
    const size_t g = (size_t)blockIdx.x * 256 + threadIdx.x;
    const size_t stride = (size_t)SB * SE * SN;
    float h = 0.f;
    float P = Pbuf[g], S = Sbuf[g];
    for (int c = 0; c < SC; c++) {
        float Pn = 0.f, Sn = 0.f;
        if (c + 1 < SC) {
            Pn = Pbuf[(c + 1) * stride + g];
            Sn = Sbuf[(c + 1) * stride + g];
        }
        hinit[c * stride + g] = h;
        h = fmaf(P, h, S);
        P = Pn; S = Sn;
    }
}

__global__ __launch_bounds__(256) void scan_pass3(
    const float* __restrict__ delta, const float* __restrict__ u,
    const float* __restrict__ proj, const float* __restrict__ A_log,
    const float* __restrict__ Dp, const float* __restrict__ xr,
    const float* __restrict__ hinit, ushort* __restrict__ yg)
{
    __shared__ float sB[ST * SN];
    __shared__ float sC[ST * SN];
    const int tid = threadIdx.x;
    const int eb = blockIdx.x & 7;
    const int c  = (blockIdx.x >> 3) & (SC - 1);
    const int b  = blockIdx.x >> 9;
    const int e  = eb * 256 + tid;
    const size_t row0 = (size_t)b * SL + c * ST;

    for (int i = tid; i < ST * SN; i += 256) {
        const int tl = i >> 4, n = i & 15;
        sB[i] = proj[(row0 + tl) * 160 + 128 + n];
        sC[i] = proj[(row0 + tl) * 160 + 144 + n];
    }
    __syncthreads();

    float An[SN], h[SN];
    {
        const float4* Ap = (const float4*)(A_log + (size_t)e * SN);
#pragma unroll
        for (int q = 0; q < 4; q++) {
            float4 v = Ap[q];
            An[q * 4 + 0] = -expf(v.x);
            An[q * 4 + 1] = -expf(v.y);
            An[q * 4 + 2] = -expf(v.z);
            An[q * 4 + 3] = -expf(v.w);
        }
    }
    {
        const size_t ib = ((((size_t)c * SB) + b) * SE + e) * SN;
#pragma unroll
        for (int q = 0; q < 4; q++) {
            float4 v = *(const float4*)(hinit + ib + q * 4);
            h[q * 4 + 0] = v.x; h[q * 4 + 1] = v.y;
            h[q * 4 + 2] = v.z; h[q * 4 + 3] = v.w;
        }
    }
    const float De = Dp[e];

    size_t idx = row0 * SE + e;
    float d = delta[idx], uu = u[idx], g = xr[idx];
    for (int tl = 0; tl < ST; tl++) {
        float dn = 0.f, un = 0.f, gn = 0.f;
        if (tl + 1 < ST) {
            dn = delta[idx + SE]; un = u[idx + SE]; gn = xr[idx + SE];
        }
        const float du = d * uu;
        float y = 0.f;
#pragma unroll
        for (int n = 0; n < SN; n++) {
            const float dA = __expf(d * An[n]);
            h[n] = fmaf(dA, h[n], du * sB[tl * SN + n]);
            y = fmaf(h[n], sC[tl * SN + n], y);
        }
        yg[idx] = f2bf((y + uu * De) * g);
        d = dn; uu = un; g = gn; idx += SE;
    }
}

extern "C" void kernel_launch(void* const* d_in, const int* in_sizes, int n_in,
                              void* d_out, int out_size, void* d_ws, size_t ws_size,
                              hipStream_t stream)
{
    const int Bc = 2, Lc = 2048, Hc = 1024, Ec = 2048;
    const int M = Bc * Lc;      // 4096
    const int PN = 160;
    const int SKZ = 8;          // GEMM3 split-K factor

    const float* x        = (const float*)d_in[0];
    const float* W_in     = (const float*)d_in[1];
    const float* b_in     = (const float*)d_in[2];
    const float* conv_w   = (const float*)d_in[3];
    const float* conv_b   = (const float*)d_in[4];
    const float* x_proj_w = (const float*)d_in[5];
    const float* dt_proj_w= (const float*)d_in[6];
    const float* dt_bias  = (const float*)d_in[7];
    const float* A_log    = (const float*)d_in[8];
    const float* D_param  = (const float*)d_in[9];
    const float* W_out    = (const float*)d_in[10];
    const float* b_out    = (const float*)d_in[11];
    float* out = (float*)d_out;

    float* ws = (float*)d_ws;
    const size_t ME = (size_t)M * Ec;            // 8,388,608 floats
    const size_t PS = (size_t)SB * SE * SC * SN; // 4,194,304 floats

    // region map (floats):
    float* xc_raw = ws;                  // region0: GEMM1 out / Pp3 / P,S / ygbf
    float* xr     = xc_raw + ME;         // region1: xr, later GEMM6 partials
    float* xc     = xr + ME;             // region2: W_in_t early, then conv out fp32
    float* delta  = xc + ME;             // region3: xbf, xc_bf, delta, then W_out_t
    float* proj   = delta + ME;
    float* hinit  = proj + (size_t)M * PN;  // also hosts xpw_t/dtw_t/dtbf pre-pass2

    ushort* xbf    = (ushort*)delta;
    ushort* W_in_t = (ushort*)xc;
    ushort* xc_bf  = (ushort*)delta;
    float*  Pp3    = xc_raw;                 // SKZ*M*160 = 5.24M floats
    ushort* xpw_t  = (ushort*)hinit;
    ushort* dtw_t  = (ushort*)hinit + 327680;
    ushort* dtbf   = (ushort*)hinit + 327680 + 262144;
    float*  Pbuf   = xc_raw;
    float*  Sbuf   = xc_raw + PS;
    ushort* ygbf   = (ushort*)xc_raw;
    ushort* W_out_t= (ushort*)delta;
    float*  Pp6    = xr;                     // 2*M*1024 = 8.4M floats (xr dead)

    // 0) dtype conversions / weight transposes
    f2bf_vec<<<1024, 256, 0, stream>>>(x, xbf, (size_t)M * Hc / 4);
    f2bf_transpose<<<dim3(2 * Ec / 32, Hc / 32), 256, 0, stream>>>(
        W_in, W_in_t, Hc, 2 * Ec);
    f2bf_transpose<<<dim3(PN / 32, Ec / 32), 256, 0, stream>>>(
        x_proj_w, xpw_t, Ec, PN);
    f2bf_transpose<<<dim3(Ec / 32, 128 / 32), 256, 0, stream>>>(
        dt_proj_w, dtw_t, 128, Ec);

    // 1) z = x @ W_in + b_in ; split -> xc_raw (fp32), silu -> xr (fp32)
    hgemm2<EP_SPLIT_SILU><<<dim3(2 * Ec / 128, M / 128, 1), 256, 0, stream>>>(
        xbf, W_in_t, xc_raw, b_in, xr, M, 2 * Ec, Hc, Ec, Hc);

    // 2) depthwise causal conv + bias + silu -> xc (fp32) + xc_bf (bf16)
    conv_silu4<<<2048, 256, 0, stream>>>(
        xc_raw, conv_w, conv_b, xc, xc_bf, Lc, Ec, ME / 4);

    // 3) proj = xc @ x_proj_w : split-K bf16 MFMA + reduce (emits dt bf16 too)
    hgemm2<EP_PARTIAL><<<dim3(2, M / 128, SKZ), 256, 0, stream>>>(
        xc_bf, xpw_t, Pp3, nullptr, nullptr, M, PN, Ec, 0, Ec / SKZ);
    gemm3_reduce<<<(M * PN + 255) / 256, 256, 0, stream>>>(
        Pp3, proj, dtbf, M, PN, SKZ);

    // 4) delta = softplus(dt @ dt_proj_w + dt_bias) : bf16 MFMA
    hgemm2<EP_SOFTPLUS><<<dim3(Ec / 128, M / 128, 1), 256, 0, stream>>>(
        dtbf, dtw_t, delta, dt_bias, nullptr, M, Ec, 128, 0, 128);

    // 5) chunked parallel scan; pass3 emits bf16 yg
    scan_pass1<<<SB * SC * (SE / 256), 256, 0, stream>>>(
        delta, xc, proj, A_log, Pbuf, Sbuf);
    scan_pass2<<<(SB * SE * SN) / 256, 256, 0, stream>>>(Pbuf, Sbuf, hinit);
    scan_pass3<<<SB * SC * (SE / 256), 256, 0, stream>>>(
        delta, xc, proj, A_log, D_param, xr, hinit, ygbf);

    // 5b) W_out (E x H) -> bf16 (H x E)   (delta region dead now)
    f2bf_transpose<<<dim3(Hc / 32, Ec / 32), 256, 0, stream>>>(
        W_out, W_out_t, Ec, Hc);

    // 6) out = yg @ W_out : split-K=2 partials + bias reduce
    hgemm2<EP_PARTIAL><<<dim3(Hc / 128, M / 128, 2), 256, 0, stream>>>(
        ygbf, W_out_t, Pp6, nullptr, nullptr, M, Hc, Ec, 0, Ec / 2);
    reduce6<<<(M * Hc + 255) / 256, 256, 0, stream>>>(Pp6, b_out, out, M, Hc);
}